// Round 19
// baseline (175.753 us; speedup 1.0000x reference)
//
#include <hip/hip_runtime.h>
#include <math.h>

#define BATCH 8
constexpr float DXC   = 2.0f/31.0f;
constexpr float DXDY  = DXC*DXC;
constexpr float SCALE = 0.125f;      // 1/sqrt(64), folded into M/u/v/c at reduce
constexpr float EPSC  = 1e-5f;
constexpr float SLOPEC= 0.01f;

// ---- workspace float offsets ----
#define OFF_LNP    0u         // 256
#define OFF_M      256u       // 16384
#define OFF_U      16640u     // 256
#define OFF_V      16896u     // 256
#define OFF_C      17152u     // 16
#define OFF_WSP2   17168u     // 32768 (2 mat x 16 nt x 1024 jj colsum partials)
#define OFF_VIN    150288u    // 1048576
#define OFF_W      1198864u   // 1048576
#define OFF_WF     2247440u   // 1048576
#define OFF_GPA    3296016u   // 1048576 (gram partials A; P ns0 at the end)
#define OFF_GSA    4344592u   // 16384
#define OFF_GPB    4360976u   // 1048576 (lower: cross-gram; upper: P ns1)
#define OFF_GSB    5409552u   // 16384
#define OFF_P      5425936u   // 1048576 floats = 4MB: Wt + Wft as bf16
#define OFF_BJT    6474512u   // 65536 (Bj table: [which][j][32c] f32, 256 KB)
// prep partial layout inside GPB (pre-layer0): per (j,ch) stride 4352
#define MP_STRIDE  4352

typedef short bf16x8 __attribute__((ext_vector_type(8)));
typedef float f32x4  __attribute__((ext_vector_type(4)));

struct MlpW {
  const float *kW0,*kb0,*kW1,*kb1,*kW2,*kb2;
  const float *fW0,*fb0,*fW1,*fb1,*fW2,*fb2;
  const float *bjt;
  float *wo, *wfo;
};

__device__ __forceinline__ unsigned cvt2bf(float a, float b){
  unsigned r; asm("v_cvt_pk_bf16_f32 %0, %1, %2" : "=v"(r) : "v"(a), "v"(b)); return r;
}

__device__ __forceinline__ float lrelu(float x){ return fmaxf(x, SLOPEC*x); }

__device__ __forceinline__ float wsum64(float v){
  #pragma unroll
  for(int off=32; off; off>>=1) v += __shfl_xor(v, off);
  return v;
}

// -------- one edge-MLP unit (which,i) over all 1024 j, by 4 waves (swid 0..3) ------
// H-build uses the precomputed Bj table (i-independent part hoisted device-wide);
// jt loop unrolled x2 for dep-chain overlap; epilogue has 4 independent chains.
__device__ __forceinline__ void mlp_unit(const MlpW P, int unit, int swid, int lane)
{
  int which = unit>>10, i = unit&1023;
  const float* W0 = which? P.fW0:P.kW0; const float* b0 = which? P.fb0:P.kb0;
  const float* W1 = which? P.fW1:P.kW1; const float* b1 = which? P.fb1:P.kb1;
  const float* W2 = which? P.fW2:P.kW2; const float* b2 = which? P.fb2:P.kb2;
  const float* bj = P.bjt + which*32768;
  float* outp = which? P.wfo : P.wo;
  int grp = lane>>4, jl = lane&15;
  float xi = -1.f + DXC*(float)(i>>5), yi = -1.f + DXC*(float)(i&31);
  float a0c[8];
  #pragma unroll
  for(int t=0;t<8;t++){
    int c = grp*8+t;
    float4 w0 = *(const float4*)(W0 + c*4);
    a0c[t] = w0.x*xi + w0.y*yi + b0[c];
  }
  bf16x8 afr[4];
  #pragma unroll
  for(int ot=0;ot<4;ot++){
    const float* src = W1 + (ot*16+jl)*32 + grp*8;
    uint4 p;
    p.x=cvt2bf(src[0],src[1]); p.y=cvt2bf(src[2],src[3]);
    p.z=cvt2bf(src[4],src[5]); p.w=cvt2bf(src[6],src[7]);
    afr[ot] = __builtin_bit_cast(bf16x8, p);
  }
  float b1v[16], w2v[16];
  #pragma unroll
  for(int ot=0;ot<4;ot++){
    #pragma unroll
    for(int r=0;r<4;r++){
      int o = ot*16 + grp*4 + r;
      b1v[ot*4+r] = b1[o];
      w2v[ot*4+r] = W2[o];
    }
  }
  float b2s = b2[0];
  f32x4 zz = {0.f,0.f,0.f,0.f};
  int jbase = swid*256;
  #pragma unroll 2
  for(int jt=0;jt<16;jt++){
    int j0 = jbase + jt*16;
    const float* bp = bj + (j0+jl)*32 + grp*8;   // coalesced 2KB/wave, L2-hit
    float4 bv0 = *(const float4*)bp;
    float4 bv1 = *(const float4*)(bp+4);
    float h[8];
    h[0]=lrelu(a0c[0]+bv0.x); h[1]=lrelu(a0c[1]+bv0.y);
    h[2]=lrelu(a0c[2]+bv0.z); h[3]=lrelu(a0c[3]+bv0.w);
    h[4]=lrelu(a0c[4]+bv1.x); h[5]=lrelu(a0c[5]+bv1.y);
    h[6]=lrelu(a0c[6]+bv1.z); h[7]=lrelu(a0c[7]+bv1.w);
    uint4 hb;
    hb.x=cvt2bf(h[0],h[1]); hb.y=cvt2bf(h[2],h[3]);
    hb.z=cvt2bf(h[4],h[5]); hb.w=cvt2bf(h[6],h[7]);
    bf16x8 bfr = __builtin_bit_cast(bf16x8, hb);
    f32x4 d0 = __builtin_amdgcn_mfma_f32_16x16x32_bf16(afr[0], bfr, zz, 0,0,0);
    f32x4 d1 = __builtin_amdgcn_mfma_f32_16x16x32_bf16(afr[1], bfr, zz, 0,0,0);
    f32x4 d2 = __builtin_amdgcn_mfma_f32_16x16x32_bf16(afr[2], bfr, zz, 0,0,0);
    f32x4 d3 = __builtin_amdgcn_mfma_f32_16x16x32_bf16(afr[3], bfr, zz, 0,0,0);
    float p0=0.f, p1=0.f, p2=0.f, p3=0.f;       // 4 independent chains
    #pragma unroll
    for(int r=0;r<4;r++){
      float s0 = d0[r]+b1v[r];    p0 = fmaf(w2v[r],    fmaxf(s0,SLOPEC*s0), p0);
      float s1 = d1[r]+b1v[4+r];  p1 = fmaf(w2v[4+r],  fmaxf(s1,SLOPEC*s1), p1);
      float s2 = d2[r]+b1v[8+r];  p2 = fmaf(w2v[8+r],  fmaxf(s2,SLOPEC*s2), p2);
      float s3 = d3[r]+b1v[12+r]; p3 = fmaf(w2v[12+r], fmaxf(s3,SLOPEC*s3), p3);
    }
    float part = (p0+p1) + (p2+p3);
    part += __shfl_xor(part, 16);
    part += __shfl_xor(part, 32);
    if(lane<16) outp[i*1024 + j0 + lane] = part + b2s;
  }
}

// -------- transpose+bf16 one 64x64 tile of weight -> Wt[jj][n], + colsum partial ----
__device__ __forceinline__ void transpose_unit(const float* __restrict__ src,
    unsigned short* __restrict__ dst, float* __restrict__ wsp2row,
    int n0, int jj0, unsigned short* S, int utid)
{
  int np = utid&31, jq = utid>>5;             // np 0..31 (n-pairs), jq 0..7 (8 jj each)
  const float* r0 = src + (size_t)(n0 + 2*np)*1024 + jj0 + jq*8;
  const float* r1 = r0 + 1024;
  float av[8], bv[8];
  *(float4*)&av[0] = *(const float4*)r0;  *(float4*)&av[4] = *(const float4*)(r0+4);
  *(float4*)&bv[0] = *(const float4*)r1;  *(float4*)&bv[4] = *(const float4*)(r1+4);
  unsigned* S32 = (unsigned*)S;
  #pragma unroll
  for(int e=0;e<8;e++)
    S32[((jq*8+e)*72 + 2*np)>>1] = cvt2bf(av[e], bv[e]);   // lo=n even, hi=n odd
  __syncthreads();
  int jl = utid>>2, seg = utid&3;
  uint4 s0 = *(uint4*)&S[jl*72 + seg*16];
  uint4 s1 = *(uint4*)&S[jl*72 + seg*16 + 8];
  unsigned short* orow = dst + (size_t)(jj0+jl)*1024 + n0 + seg*16;
  *(uint4*)orow = s0;
  *(uint4*)(orow+8) = s1;
  if(utid < 64){
    const unsigned* Sr = (const unsigned*)&S[utid*72];
    float acc = 0.f;
    #pragma unroll
    for(int h=0;h<32;h++){
      unsigned v = Sr[h];
      acc += __builtin_bit_cast(float, v<<16);
      acc += __builtin_bit_cast(float, v & 0xffff0000u);
    }
    wsp2row[jj0 + utid] = acc;
  }
}

// ------- first launch: prep PARTIALS + LN0 partials + Bj table -------
__global__ __launch_bounds__(256) void k_pre(
    const float* __restrict__ xy,
    const float* __restrict__ Wq, const float* __restrict__ bq,
    const float* __restrict__ Wk, const float* __restrict__ bk,
    const float* __restrict__ kW0, const float* __restrict__ fW0,
    float* __restrict__ ws)
{
  __shared__ float red[8];
  int blk = blockIdx.x, tid = threadIdx.x;
  int lane = tid&63;
  int wid = __builtin_amdgcn_readfirstlane(tid>>6);
  if(blk < 64){
    int j = blk>>4, ch = blk&15;
    float mac[16], uac[16];
    #pragma unroll
    for(int r=0;r<16;r++){ mac[r]=0.f; uac[r]=0.f; }
    float vac=0.f, cac=0.f;
    #pragma unroll 4
    for(int hk=ch*16; hk<ch*16+16; hk++){
      const float* wqrow = Wq + ((size_t)j*256+hk)*64;
      const float* wkrow = Wk + ((size_t)j*256+hk)*64;
      float wkl = wkrow[lane];
      float bkk = bk[j*256+hk], bqk = bq[j*256+hk];
      #pragma unroll
      for(int r=0;r<16;r++){ float wq=wqrow[wid*16+r]; mac[r]+=wq*wkl; uac[r]+=wq*bkk; }
      vac += bqk*wkl; cac += bqk*bkk;
    }
    float* mp = ws + OFF_GPB + (size_t)(j*16+ch)*MP_STRIDE;
    #pragma unroll
    for(int r=0;r<16;r++) mp[(wid*16+r)*64+lane] = mac[r];
    if(lane==0){
      #pragma unroll
      for(int r=0;r<16;r++) mp[4096 + wid*16+r] = uac[r];
    }
    if(wid==0) mp[4160+lane] = vac;
    if(tid==0) mp[4224] = cac;
  } else if(blk < 192){
    int bb = blk-64;                             // 128 blocks
    int b = bb>>4, seg = bb&15;
    const float4* x4 = (const float4*)(xy + (size_t)b*131072 + seg*8192);
    float s=0.f, ss=0.f;
    #pragma unroll
    for(int k2=0;k2<8;k2++){
      float4 v = x4[tid + k2*256];
      s  += v.x+v.y+v.z+v.w;
      ss += v.x*v.x+v.y*v.y+v.z*v.z+v.w*v.w;
    }
    s = wsum64(s); ss = wsum64(ss);
    if(lane==0){ red[wid]=s; red[4+wid]=ss; }
    __syncthreads();
    if(tid==0){
      ws[OFF_LNP + (b*16+seg)*2  ] = red[0]+red[1]+red[2]+red[3];
      ws[OFF_LNP + (b*16+seg)*2+1] = red[4]+red[5]+red[6]+red[7];
    }
  } else {
    // blocks 192-199: Bj table (i-independent half of the edge MLP first layer)
    int idx = (blk-192)*256 + tid;               // 0..2047 = which*1024 + j
    int which = idx>>10, j = idx&1023;
    const float* W0 = which? fW0 : kW0;
    float xj = -1.f + DXC*(float)(j>>5), yj = -1.f + DXC*(float)(j&31);
    float* dst = ws + OFF_BJT + (size_t)idx*32;
    #pragma unroll
    for(int c=0;c<32;c++){
      float4 w0 = *(const float4*)(W0 + c*4);
      dst[c] = w0.z*xj + w0.w*yj;
    }
  }
}

// ---------------- Gram of 64x64 LDS tiles (8 waves: 8 cols each) ----------------
__device__ __forceinline__ void gram_tile8(const float* sA, const float* sB,
    int wid, int lane, float* __restrict__ gp, float* __restrict__ gsp)
{
  float acc[8];
  #pragma unroll
  for(int q=0;q<8;q++) acc[q]=0.f;
  float gsa=0.f;
  for(int m=0;m<64;m++){
    const float4* cp = (const float4*)(sA + m*64 + wid*8);
    float bml = sB[m*64+lane];
    float4 a0=cp[0],a1=cp[1];
    acc[0]+=a0.x*bml; acc[1]+=a0.y*bml; acc[2]+=a0.z*bml; acc[3]+=a0.w*bml;
    acc[4]+=a1.x*bml; acc[5]+=a1.y*bml; acc[6]+=a1.z*bml; acc[7]+=a1.w*bml;
    gsa += bml;
  }
  #pragma unroll
  for(int q=0;q<8;q++) gp[(wid*8+q)*64+lane]=acc[q];
  if(wid==0) gsp[lane]=gsa;
}

// ---------------- T build from LDS Gram (8 waves: 8 rows each) ----------------
__device__ __forceinline__ void build_T8(const float* __restrict__ sG,
    const float* __restrict__ Mj, const float* __restrict__ uj,
    const float* __restrict__ vj, float cj, float gsl,
    int wid, int lane, float* __restrict__ sT, float* __restrict__ stv)
{
  float gv[64];
  #pragma unroll
  for(int c=0;c<64;c++) gv[c]=sG[c*64+lane];
  float tacc = cj*gsl;
  #pragma unroll
  for(int c=0;c<64;c++) tacc += vj[c]*gv[c];
  #pragma unroll
  for(int rr=0;rr<8;rr++){
    int r = wid*8+rr;
    const float* mrow = Mj + r*64;                // wave-uniform -> s_load
    float acc = uj[r]*gsl;
    #pragma unroll
    for(int c=0;c<64;c++) acc += mrow[c]*gv[c];
    sT[r*64+lane]=acc;
  }
  if(wid==0) stv[lane]=tacc;
}

// ------- LN0 apply + Gram (512 thr) + MLP ride-along + prep-reduce blocks ---------
__global__ __launch_bounds__(512) void k_ln0ag(const float* __restrict__ xy,
    const float* __restrict__ g, const float* __restrict__ bb,
    const float* __restrict__ lnp,
    float* __restrict__ Vin, float* __restrict__ Gpart, float* __restrict__ gspart,
    MlpW P, int mlp_off, float* __restrict__ ws)
{
  __shared__ float sV[4096];
  int blk = blockIdx.x;
  int tid = threadIdx.x, lane = tid&63;
  int wid = __builtin_amdgcn_readfirstlane(tid>>6);
  if(blk >= 598){
    int j = blk-598;
    const float* mp0 = ws + OFF_GPB + (size_t)(j*16)*MP_STRIDE;
    for(int e=tid; e<1024; e+=512){
      float4 s={0,0,0,0};
      for(int ch=0; ch<16; ch++){
        float4 v = *(const float4*)&mp0[(size_t)ch*MP_STRIDE + e*4];
        s.x+=v.x; s.y+=v.y; s.z+=v.z; s.w+=v.w;
      }
      s.x*=SCALE; s.y*=SCALE; s.z*=SCALE; s.w*=SCALE;
      *(float4*)&ws[OFF_M + j*4096 + e*4] = s;
    }
    if(tid<64){
      float su=0.f, sv=0.f;
      for(int ch=0; ch<16; ch++){
        su += mp0[(size_t)ch*MP_STRIDE + 4096 + tid];
        sv += mp0[(size_t)ch*MP_STRIDE + 4160 + tid];
      }
      ws[OFF_U + j*64+tid] = su*SCALE;
      ws[OFF_V + j*64+tid] = sv*SCALE;
    }
    if(tid==0){
      float sc=0.f;
      for(int ch=0; ch<16; ch++) sc += mp0[(size_t)ch*MP_STRIDE + 4224];
      ws[OFF_C + j] = sc*SCALE;
    }
    return;
  }
  if(blk >= 256){
    mlp_unit(P, mlp_off + (blk-256)*2 + (wid>>2), wid&3, lane);
    return;
  }
  int b = blk>>5, ch = blk&31;
  float s=0.f, ss=0.f;
  #pragma unroll
  for(int k2=0;k2<16;k2++){ s += lnp[(b*16+k2)*2]; ss += lnp[(b*16+k2)*2+1]; }
  float mean = s*(1.0f/131072.0f);
  float var  = ss*(1.0f/131072.0f) - mean*mean;
  float inv  = 1.0f/sqrtf(var+EPSC);
  const float4* x4 = (const float4*)(xy + ((size_t)b*2048 + ch*64)*64);
  const float4* g4 = (const float4*)(g  + (size_t)ch*4096);
  const float4* b4 = (const float4*)(bb + (size_t)ch*4096);
  float4* vo4 = (float4*)(Vin + ((size_t)b*2048 + ch*64)*64);
  float4* sv4 = (float4*)sV;
  #pragma unroll
  for(int e=0;e<2;e++){
    int idx = tid + e*512;
    float4 xv=x4[idx], gv=g4[idx], bv=b4[idx];
    float4 r;
    r.x=(xv.x-mean)*inv*gv.x+bv.x;
    r.y=(xv.y-mean)*inv*gv.y+bv.y;
    r.z=(xv.z-mean)*inv*gv.z+bv.z;
    r.w=(xv.w-mean)*inv*gv.w+bv.w;
    vo4[idx]=r; sv4[idx]=r;
  }
  __syncthreads();
  gram_tile8(sV, sV, wid, lane, Gpart+((size_t)(b*32+ch))*4096, gspart+(b*32+ch)*64);
}

// -------- layer (512 threads) + ride-along: MLP (emode 0) or transpose (emode 1) ---
__global__ __launch_bounds__(512) void k_layer(
    float* __restrict__ Vin, const float* __restrict__ xy,
    const float* __restrict__ Gsrc, const float* __restrict__ gssrc,
    float* __restrict__ Gdst, float* __restrict__ gsdst,
    const float* __restrict__ Mg, const float* __restrict__ ug,
    const float* __restrict__ vg, const float* __restrict__ cg,
    const float* __restrict__ lng, const float* __restrict__ lnb,
    int j, int cross, MlpW P, int mlp_off,
    unsigned short* __restrict__ wtg, unsigned short* __restrict__ wftg,
    float* __restrict__ wsp2, int emode)
{
  __shared__ __align__(16) float sV[4096];
  __shared__ __align__(16) float sT[4096];
  __shared__ __align__(16) float sG[4096];
  __shared__ float stv[64];
  int blk = blockIdx.x, tid = threadIdx.x;
  int lane = tid&63;
  int wid = __builtin_amdgcn_readfirstlane(tid>>6);
  if(blk >= 256){
    if(emode == 0){
      mlp_unit(P, mlp_off + (blk-256)*2 + (wid>>2), wid&3, lane);
    } else {
      int half = tid>>8;                          // waves 0-3 / 4-7
      int unit = (blk-256)*2 + half;              // 0..511
      int utid = tid & 255;
      int mat = unit>>8, tile = unit&255;
      int nt = tile>>4, jt = tile&15;
      unsigned short* S = (unsigned short*)(half? sT : sV);
      transpose_unit(mat? P.wfo : P.wo, mat? wftg : wtg,
                     wsp2 + (mat*16 + nt)*1024, nt*64, jt*64, S, utid);
    }
    return;
  }
  int b = blk>>5, ch = blk&31;
  float* vbase = Vin + ((size_t)b*2048 + ch*64)*64;
  {
    const float4* vb4=(const float4*)vbase;
    float4* sv4=(float4*)sV;
    #pragma unroll
    for(int e=0;e<2;e++) sv4[tid+e*512]=vb4[tid+e*512];
  }
  {
    float4 a0={0,0,0,0},a1={0,0,0,0};
    const float4* gp4 = (const float4*)(Gsrc + (size_t)b*32*4096) + tid*2;
    for(int c=0;c<32;c++){
      const float4* p = gp4 + c*1024;
      float4 v0=p[0],v1=p[1];
      a0.x+=v0.x;a0.y+=v0.y;a0.z+=v0.z;a0.w+=v0.w;
      a1.x+=v1.x;a1.y+=v1.y;a1.z+=v1.z;a1.w+=v1.w;
    }
    float4* sg4=(float4*)sG + tid*2;
    sg4[0]=a0; sg4[1]=a1;
  }
  float gsl=0.f;
  for(int c=0;c<32;c++) gsl += gssrc[(b*32+c)*64+lane];
  __syncthreads();
  build_T8(sG, Mg+j*4096, ug+j*64, vg+j*64, cg[j], gsl, wid, lane, sT, stv);
  __syncthreads();
  float Tcol[64];
  #pragma unroll
  for(int c=0;c<64;c++) Tcol[c]=sT[c*64+lane];
  float tvl=stv[lane];
  float gl=lng[j*64+lane], bl=lnb[j*64+lane];
  #pragma unroll
  for(int rr=0;rr<8;rr++){
    int r=wid*8+rr;
    const float4* rp=(const float4*)(sV + r*64);
    float vold = sV[r*64+lane];
    float m=tvl;
    #pragma unroll
    for(int c4=0;c4<16;c4++){
      float4 vv=rp[c4];
      m += vv.x*Tcol[c4*4]+vv.y*Tcol[c4*4+1]+vv.z*Tcol[c4*4+2]+vv.w*Tcol[c4*4+3];
    }
    m*=DXDY;
    float mean=wsum64(m)*(1.f/64.f);
    float d=m-mean;
    float var=wsum64(d*d)*(1.f/64.f);
    float y=d*(1.f/sqrtf(var+EPSC))*gl+bl+vold;
    vbase[r*64+lane]=y;
    sV[r*64+lane]=y;
  }
  __syncthreads();
  if(!cross){
    gram_tile8(sV, sV, wid, lane, Gdst+((size_t)(b*32+ch))*4096, gsdst+(b*32+ch)*64);
  } else if(ch<16){
    const float4* x4=(const float4*)(xy + ((size_t)b*2048+ch*64)*64);
    float4* sx4=(float4*)sG;
    #pragma unroll
    for(int e=0;e<2;e++) sx4[tid+e*512]=x4[tid+e*512];
    __syncthreads();
    gram_tile8(sV, sG, wid, lane, Gdst+((size_t)(b*16+ch))*4096, gsdst+(b*16+ch)*64);
  }
}

// ------ P = Wt^T-GEMM via MFMA: D[16jj x 64f] per wave, K=512 per block (ns=2) -----
__global__ __launch_bounds__(256) void k_pw(
    const unsigned short* __restrict__ WtG, const unsigned short* __restrict__ WftG,
    const float* __restrict__ Vin,
    float* __restrict__ P0, float* __restrict__ P1)
{
  __shared__ __align__(16) unsigned short sVu[64*72];   // [f][n-padded] bf16
  __shared__ __align__(16) unsigned short sVf[64*72];
  int bid = blockIdx.x;                 // 256 = b(8) x jjc(16) x ns(2)
  int ns = bid&1, jjc = (bid>>1)&15, b = bid>>5;
  int tid = threadIdx.x, lane = tid&63;
  int wid = __builtin_amdgcn_readfirstlane(tid>>6);
  int jl = lane&15, grp = lane>>4;
  int jjw = jjc*64 + wid*16;
  const float* Vu = Vin + (size_t)b*131072;
  const float* Vf = Vu + 65536;
  f32x4 acc[4] = {{0,0,0,0},{0,0,0,0},{0,0,0,0},{0,0,0,0}};
  int np = tid&31, fq = tid>>5;         // staging: 32 n-pairs x 8 f-groups
  unsigned* Su = (unsigned*)sVu;
  unsigned* Sf = (unsigned*)sVf;
  for(int step=0; step<8; step++){
    int nb = ns*512 + step*64;
    {
      const float* u0 = Vu + (size_t)(nb + 2*np)*64 + fq*8;
      const float* f0 = Vf + (size_t)(nb + 2*np)*64 + fq*8;
      float ua[8], ub[8], fa[8], fb[8];
      *(float4*)&ua[0] = *(const float4*)u0;      *(float4*)&ua[4] = *(const float4*)(u0+4);
      *(float4*)&ub[0] = *(const float4*)(u0+64); *(float4*)&ub[4] = *(const float4*)(u0+68);
      *(float4*)&fa[0] = *(const float4*)f0;      *(float4*)&fa[4] = *(const float4*)(f0+4);
      *(float4*)&fb[0] = *(const float4*)(f0+64); *(float4*)&fb[4] = *(const float4*)(f0+68);
      #pragma unroll
      for(int e=0;e<8;e++){
        Su[((fq*8+e)*72 + 2*np)>>1] = cvt2bf(ua[e], ub[e]);
        Sf[((fq*8+e)*72 + 2*np)>>1] = cvt2bf(fa[e], fb[e]);
      }
    }
    __syncthreads();
    #pragma unroll
    for(int ks=0; ks<2; ks++){
      int kk = ks*32;
      bf16x8 aw  = *(const bf16x8*)&WtG [(size_t)(jjw+jl)*1024 + nb + kk + grp*8];
      bf16x8 awf = *(const bf16x8*)&WftG[(size_t)(jjw+jl)*1024 + nb + kk + grp*8];
      #pragma unroll
      for(int ft=0; ft<4; ft++){
        bf16x8 bu = *(const bf16x8*)&sVu[(ft*16+jl)*72 + kk + grp*8];
        bf16x8 bv = *(const bf16x8*)&sVf[(ft*16+jl)*72 + kk + grp*8];
        acc[ft] = __builtin_amdgcn_mfma_f32_16x16x32_bf16(aw,  bu, acc[ft], 0,0,0);
        acc[ft] = __builtin_amdgcn_mfma_f32_16x16x32_bf16(awf, bv, acc[ft], 0,0,0);
      }
    }
    __syncthreads();
  }
  float* Pd = (ns? P1 : P0) + ((size_t)b*1024 + jjw)*64;
  #pragma unroll
  for(int ft=0; ft<4; ft++){
    #pragma unroll
    for(int r=0;r<4;r++){
      int row = grp*4 + r;
      Pd[(size_t)row*64 + ft*16 + jl] = acc[ft][r];
    }
  }
}

// ---------------- final (512 threads): redundant T3 build + out ----------------
__global__ __launch_bounds__(512) void k_final(
    const float* __restrict__ Gp2, const float* __restrict__ gsp2,
    const float* __restrict__ Mg, const float* __restrict__ ug,
    const float* __restrict__ vg, const float* __restrict__ cg,
    const float* __restrict__ P0, const float* __restrict__ P1,
    const float* __restrict__ wsp2,
    float* __restrict__ out)
{
  __shared__ float sG[4096];
  __shared__ float sT[4096];
  __shared__ float stv[64];
  int blk = blockIdx.x, tid = threadIdx.x;       // grid 256
  int lane = tid&63;
  int wid = __builtin_amdgcn_readfirstlane(tid>>6);
  int b = blk>>5, rg = blk&31;
  {
    float4 a0={0,0,0,0},a1={0,0,0,0};
    const float4* gp4 = (const float4*)(Gp2 + (size_t)b*16*4096) + tid*2;
    for(int c=0;c<16;c++){
      const float4* p = gp4 + c*1024;
      float4 v0=p[0],v1=p[1];
      a0.x+=v0.x;a0.y+=v0.y;a0.z+=v0.z;a0.w+=v0.w;
      a1.x+=v1.x;a1.y+=v1.y;a1.z+=v1.z;a1.w+=v1.w;
    }
    float4* sg4=(float4*)sG + tid*2;
    sg4[0]=a0; sg4[1]=a1;
  }
  float gsl=0.f;
  for(int c=0;c<16;c++) gsl += gsp2[(b*16+c)*64+lane];
  __syncthreads();
  build_T8(sG, Mg+3*4096, ug+3*64, vg+3*64, cg[3], gsl, wid, lane, sT, stv);
  __syncthreads();
  float Tcol[64];
  #pragma unroll
  for(int c=0;c<64;c++) Tcol[c]=sT[c*64+lane];
  float t3l=stv[lane];
  #pragma unroll
  for(int rw=0;rw<4;rw++){
    int jj=rg*32+wid*4+rw;
    float p = P0[((size_t)b*1024+jj)*64+lane]
            + P1[((size_t)b*1024+jj)*64+lane];
    float wsm = 0.f;
    #pragma unroll
    for(int c=0;c<32;c++) wsm += wsp2[c*1024+jj];
    float acc=wsm*t3l;
    #pragma unroll
    for(int c=0;c<64;c++) acc += __shfl(p,c)*Tcol[c];
    out[((size_t)(b*1024)+jj)*64+lane]=acc*(DXDY*DXDY);
  }
}

extern "C" void kernel_launch(void* const* d_in, const int* in_sizes, int n_in,
                              void* d_out, int out_size, void* d_ws, size_t ws_size,
                              hipStream_t stream)
{
  (void)in_sizes; (void)n_in; (void)out_size; (void)ws_size;
  const float* xy   = (const float*)d_in[0];
  const float* kW0  = (const float*)d_in[1];
  const float* kb0  = (const float*)d_in[2];
  const float* kW1  = (const float*)d_in[3];
  const float* kb1  = (const float*)d_in[4];
  const float* kW2  = (const float*)d_in[5];
  const float* kb2  = (const float*)d_in[6];
  const float* fW0  = (const float*)d_in[7];
  const float* fb0  = (const float*)d_in[8];
  const float* fW1  = (const float*)d_in[9];
  const float* fb1  = (const float*)d_in[10];
  const float* fW2  = (const float*)d_in[11];
  const float* fb2  = (const float*)d_in[12];
  const float* Wq   = (const float*)d_in[13];
  const float* bq   = (const float*)d_in[14];
  const float* Wk   = (const float*)d_in[15];
  const float* bk   = (const float*)d_in[16];
  const float* ln0g = (const float*)d_in[17];
  const float* ln0b = (const float*)d_in[18];
  const float* lng  = (const float*)d_in[19];
  const float* lnb  = (const float*)d_in[20];
  float* out = (float*)d_out;
  float* ws  = (float*)d_ws;

  float* lnp    = ws+OFF_LNP;
  float* Mg     = ws+OFF_M;
  float* ug     = ws+OFF_U;
  float* vg     = ws+OFF_V;
  float* cg     = ws+OFF_C;
  float* wsp2   = ws+OFF_WSP2;
  float* Vin    = ws+OFF_VIN;
  float* weight = ws+OFF_W;
  float* weightf= ws+OFF_WF;
  float* GPA    = ws+OFF_GPA;
  float* GSA    = ws+OFF_GSA;
  float* GPB    = ws+OFF_GPB;
  float* GSB    = ws+OFF_GSB;
  unsigned short* Wt  = (unsigned short*)(ws+OFF_P);
  unsigned short* Wft = Wt + 1048576;
  float* P1 = GPB + 524288;            // GPB upper half (lower = cross-gram)

  MlpW P = {kW0,kb0,kW1,kb1,kW2,kb2, fW0,fb0,fW1,fb1,fW2,fb2,
            ws+OFF_BJT, weight, weightf};

  k_pre<<<200, 256, 0, stream>>>(xy, Wq, bq, Wk, bk, kW0, fW0, ws);
  k_ln0ag<<<602, 512, 0, stream>>>(xy, ln0g, ln0b, lnp, Vin, GPA, GSA, P, 0, ws);
  k_layer<<<597, 512, 0, stream>>>(Vin, xy, GPA, GSA, GPB, GSB,
                                   Mg, ug, vg, cg, lng, lnb, 0, 0, P, 684,
                                   Wt, Wft, wsp2, 0);
  k_layer<<<597, 512, 0, stream>>>(Vin, xy, GPB, GSB, GPA, GSA,
                                   Mg, ug, vg, cg, lng, lnb, 1, 0, P, 1366,
                                   Wt, Wft, wsp2, 0);
  // j=2: carrier (256) + 256 transpose blocks (weight final after j=1)
  k_layer<<<512, 512, 0, stream>>>(Vin, xy, GPA, GSA, GPB, GSB,
                                   Mg, ug, vg, cg, lng, lnb, 2, 1, P, 0,
                                   Wt, Wft, wsp2, 1);

  // GPA dead after j=2 -> P ns0; GPB upper -> P ns1
  k_pw<<<256, 256, 0, stream>>>(Wt, Wft, Vin, GPA, P1);
  k_final<<<256, 512, 0, stream>>>(GPB, GSB, Mg, ug, vg, cg, GPA, P1, wsp2, out);
}

// Round 20
// 162.357 us; speedup vs baseline: 1.0825x; 1.0825x over previous
//
#include <hip/hip_runtime.h>
#include <math.h>

#define BATCH 8
constexpr float DXC   = 2.0f/31.0f;
constexpr float DXDY  = DXC*DXC;
constexpr float SCALE = 0.125f;      // 1/sqrt(64), folded into M/u/v/c at reduce
constexpr float EPSC  = 1e-5f;
constexpr float SLOPEC= 0.01f;

// ---- workspace float offsets ----
#define OFF_LNP    0u         // 256
#define OFF_M      256u       // 16384
#define OFF_U      16640u     // 256
#define OFF_V      16896u     // 256
#define OFF_C      17152u     // 16
#define OFF_WSP2   17168u     // 32768 (2 mat x 16 nt x 1024 jj colsum partials)
#define OFF_VIN    150288u    // 1048576
#define OFF_W      1198864u   // 1048576
#define OFF_WF     2247440u   // 1048576
#define OFF_GPA    3296016u   // 1048576 (gram partials A; P ns0 at the end)
#define OFF_GSA    4344592u   // 16384
#define OFF_GPB    4360976u   // 1048576 (lower: cross-gram; upper: P ns1)
#define OFF_GSB    5409552u   // 16384
#define OFF_P      5425936u   // 1048576 floats = 4MB: Wt + Wft as bf16
// prep partial layout inside GPB (pre-layer0): per (j,ch) stride 4352
#define MP_STRIDE  4352

typedef short bf16x8 __attribute__((ext_vector_type(8)));
typedef float f32x4  __attribute__((ext_vector_type(4)));

struct MlpW {
  const float *kW0,*kb0,*kW1,*kb1,*kW2,*kb2;
  const float *fW0,*fb0,*fW1,*fb1,*fW2,*fb2;
  float *wo, *wfo;
};

__device__ __forceinline__ unsigned cvt2bf(float a, float b){
  unsigned r; asm("v_cvt_pk_bf16_f32 %0, %1, %2" : "=v"(r) : "v"(a), "v"(b)); return r;
}

__device__ __forceinline__ float lrelu(float x){ return fmaxf(x, SLOPEC*x); }

__device__ __forceinline__ float wsum64(float v){
  #pragma unroll
  for(int off=32; off; off>>=1) v += __shfl_xor(v, off);
  return v;
}

// -------- one edge-MLP unit (which,i), one swid quarter of j (proven round-18) -----
__device__ __forceinline__ void mlp_unit(const MlpW P, int unit, int swid, int lane)
{
  int which = unit>>10, i = unit&1023;
  const float* W0 = which? P.fW0:P.kW0; const float* b0 = which? P.fb0:P.kb0;
  const float* W1 = which? P.fW1:P.kW1; const float* b1 = which? P.fb1:P.kb1;
  const float* W2 = which? P.fW2:P.kW2; const float* b2 = which? P.fb2:P.kb2;
  float* outp = which? P.wfo : P.wo;
  int grp = lane>>4, jl = lane&15;
  float xi = -1.f + DXC*(float)(i>>5), yi = -1.f + DXC*(float)(i&31);
  float a0c[8], wxc[8], wyc[8];
  #pragma unroll
  for(int t=0;t<8;t++){
    int c = grp*8+t;
    float4 w0 = *(const float4*)(W0 + c*4);
    a0c[t] = w0.x*xi + w0.y*yi + b0[c];
    wxc[t] = w0.z; wyc[t] = w0.w;
  }
  bf16x8 afr[4];
  #pragma unroll
  for(int ot=0;ot<4;ot++){
    const float* src = W1 + (ot*16+jl)*32 + grp*8;
    uint4 p;
    p.x=cvt2bf(src[0],src[1]); p.y=cvt2bf(src[2],src[3]);
    p.z=cvt2bf(src[4],src[5]); p.w=cvt2bf(src[6],src[7]);
    afr[ot] = __builtin_bit_cast(bf16x8, p);
  }
  float b1v[16], w2v[16];
  #pragma unroll
  for(int ot=0;ot<4;ot++){
    #pragma unroll
    for(int r=0;r<4;r++){
      int o = ot*16 + grp*4 + r;
      b1v[ot*4+r] = b1[o];
      w2v[ot*4+r] = W2[o];
    }
  }
  float b2s = b2[0];
  f32x4 zz = {0.f,0.f,0.f,0.f};
  int jbase = swid*256;
  for(int jt=0;jt<16;jt++){
    int j0 = jbase + jt*16;
    int j  = j0 + jl;
    float xj = -1.f + DXC*(float)(j>>5), yj = -1.f + DXC*(float)(j&31);
    float h[8];
    #pragma unroll
    for(int t=0;t<8;t++){
      float p = a0c[t] + wxc[t]*xj + wyc[t]*yj;
      h[t] = fmaxf(p, SLOPEC*p);
    }
    uint4 hb;
    hb.x=cvt2bf(h[0],h[1]); hb.y=cvt2bf(h[2],h[3]);
    hb.z=cvt2bf(h[4],h[5]); hb.w=cvt2bf(h[6],h[7]);
    bf16x8 bfr = __builtin_bit_cast(bf16x8, hb);
    f32x4 d0 = __builtin_amdgcn_mfma_f32_16x16x32_bf16(afr[0], bfr, zz, 0,0,0);
    f32x4 d1 = __builtin_amdgcn_mfma_f32_16x16x32_bf16(afr[1], bfr, zz, 0,0,0);
    f32x4 d2 = __builtin_amdgcn_mfma_f32_16x16x32_bf16(afr[2], bfr, zz, 0,0,0);
    f32x4 d3 = __builtin_amdgcn_mfma_f32_16x16x32_bf16(afr[3], bfr, zz, 0,0,0);
    float p0=0.f, p1=0.f, p2=0.f, p3=0.f;       // 4 independent chains
    #pragma unroll
    for(int r=0;r<4;r++){
      float s0 = d0[r]+b1v[r];    p0 = fmaf(w2v[r],    fmaxf(s0,SLOPEC*s0), p0);
      float s1 = d1[r]+b1v[4+r];  p1 = fmaf(w2v[4+r],  fmaxf(s1,SLOPEC*s1), p1);
      float s2 = d2[r]+b1v[8+r];  p2 = fmaf(w2v[8+r],  fmaxf(s2,SLOPEC*s2), p2);
      float s3 = d3[r]+b1v[12+r]; p3 = fmaf(w2v[12+r], fmaxf(s3,SLOPEC*s3), p3);
    }
    float part = (p0+p1) + (p2+p3);
    part += __shfl_xor(part, 16);
    part += __shfl_xor(part, 32);
    if(lane<16) outp[i*1024 + j0 + lane] = part + b2s;
  }
}

// -------- transpose+bf16 one 64x64 tile of weight -> Wt[jj][n], + colsum partial ----
__device__ __forceinline__ void transpose_unit(const float* __restrict__ src,
    unsigned short* __restrict__ dst, float* __restrict__ wsp2row,
    int n0, int jj0, unsigned short* S, int utid)
{
  int np = utid&31, jq = utid>>5;             // np 0..31 (n-pairs), jq 0..7 (8 jj each)
  const float* r0 = src + (size_t)(n0 + 2*np)*1024 + jj0 + jq*8;
  const float* r1 = r0 + 1024;
  float av[8], bv[8];
  *(float4*)&av[0] = *(const float4*)r0;  *(float4*)&av[4] = *(const float4*)(r0+4);
  *(float4*)&bv[0] = *(const float4*)r1;  *(float4*)&bv[4] = *(const float4*)(r1+4);
  unsigned* S32 = (unsigned*)S;
  #pragma unroll
  for(int e=0;e<8;e++)
    S32[((jq*8+e)*72 + 2*np)>>1] = cvt2bf(av[e], bv[e]);   // lo=n even, hi=n odd
  __syncthreads();
  int jl = utid>>2, seg = utid&3;
  uint4 s0 = *(uint4*)&S[jl*72 + seg*16];
  uint4 s1 = *(uint4*)&S[jl*72 + seg*16 + 8];
  unsigned short* orow = dst + (size_t)(jj0+jl)*1024 + n0 + seg*16;
  *(uint4*)orow = s0;
  *(uint4*)(orow+8) = s1;
  if(utid < 64){
    const unsigned* Sr = (const unsigned*)&S[utid*72];
    float acc = 0.f;
    #pragma unroll
    for(int h=0;h<32;h++){
      unsigned v = Sr[h];
      acc += __builtin_bit_cast(float, v<<16);
      acc += __builtin_bit_cast(float, v & 0xffff0000u);
    }
    wsp2row[jj0 + utid] = acc;
  }
}

// -- first launch: prep PARTIALS + LN0 partials + 512 MLP units (1 unit/256t-block) --
__global__ __launch_bounds__(256) void k_pre(
    const float* __restrict__ xy,
    const float* __restrict__ Wq, const float* __restrict__ bq,
    const float* __restrict__ Wk, const float* __restrict__ bk,
    float* __restrict__ ws, MlpW P)
{
  __shared__ float red[8];
  int blk = blockIdx.x, tid = threadIdx.x;
  int lane = tid&63;
  int wid = __builtin_amdgcn_readfirstlane(tid>>6);
  if(blk < 64){
    int j = blk>>4, ch = blk&15;
    float mac[16], uac[16];
    #pragma unroll
    for(int r=0;r<16;r++){ mac[r]=0.f; uac[r]=0.f; }
    float vac=0.f, cac=0.f;
    #pragma unroll 4
    for(int hk=ch*16; hk<ch*16+16; hk++){
      const float* wqrow = Wq + ((size_t)j*256+hk)*64;
      const float* wkrow = Wk + ((size_t)j*256+hk)*64;
      float wkl = wkrow[lane];
      float bkk = bk[j*256+hk], bqk = bq[j*256+hk];
      #pragma unroll
      for(int r=0;r<16;r++){ float wq=wqrow[wid*16+r]; mac[r]+=wq*wkl; uac[r]+=wq*bkk; }
      vac += bqk*wkl; cac += bqk*bkk;
    }
    float* mp = ws + OFF_GPB + (size_t)(j*16+ch)*MP_STRIDE;
    #pragma unroll
    for(int r=0;r<16;r++) mp[(wid*16+r)*64+lane] = mac[r];
    if(lane==0){
      #pragma unroll
      for(int r=0;r<16;r++) mp[4096 + wid*16+r] = uac[r];
    }
    if(wid==0) mp[4160+lane] = vac;
    if(tid==0) mp[4224] = cac;
  } else if(blk < 192){
    int bb = blk-64;                             // 128 blocks
    int b = bb>>4, seg = bb&15;
    const float4* x4 = (const float4*)(xy + (size_t)b*131072 + seg*8192);
    float s=0.f, ss=0.f;
    #pragma unroll
    for(int k2=0;k2<8;k2++){
      float4 v = x4[tid + k2*256];
      s  += v.x+v.y+v.z+v.w;
      ss += v.x*v.x+v.y*v.y+v.z*v.z+v.w*v.w;
    }
    s = wsum64(s); ss = wsum64(ss);
    if(lane==0){ red[wid]=s; red[4+wid]=ss; }
    __syncthreads();
    if(tid==0){
      ws[OFF_LNP + (b*16+seg)*2  ] = red[0]+red[1]+red[2]+red[3];
      ws[OFF_LNP + (b*16+seg)*2+1] = red[4]+red[5]+red[6]+red[7];
    }
  } else {
    // 512 blocks: MLP units 0..511 (4 waves = 4 swids, one unit per block)
    mlp_unit(P, blk-192, wid, lane);
  }
}

// ---------------- Gram of 64x64 LDS tiles (8 waves: 8 cols each) ----------------
__device__ __forceinline__ void gram_tile8(const float* sA, const float* sB,
    int wid, int lane, float* __restrict__ gp, float* __restrict__ gsp)
{
  float acc[8];
  #pragma unroll
  for(int q=0;q<8;q++) acc[q]=0.f;
  float gsa=0.f;
  for(int m=0;m<64;m++){
    const float4* cp = (const float4*)(sA + m*64 + wid*8);
    float bml = sB[m*64+lane];
    float4 a0=cp[0],a1=cp[1];
    acc[0]+=a0.x*bml; acc[1]+=a0.y*bml; acc[2]+=a0.z*bml; acc[3]+=a0.w*bml;
    acc[4]+=a1.x*bml; acc[5]+=a1.y*bml; acc[6]+=a1.z*bml; acc[7]+=a1.w*bml;
    gsa += bml;
  }
  #pragma unroll
  for(int q=0;q<8;q++) gp[(wid*8+q)*64+lane]=acc[q];
  if(wid==0) gsp[lane]=gsa;
}

// ---------------- T build from LDS Gram (8 waves: 8 rows each) ----------------
__device__ __forceinline__ void build_T8(const float* __restrict__ sG,
    const float* __restrict__ Mj, const float* __restrict__ uj,
    const float* __restrict__ vj, float cj, float gsl,
    int wid, int lane, float* __restrict__ sT, float* __restrict__ stv)
{
  float gv[64];
  #pragma unroll
  for(int c=0;c<64;c++) gv[c]=sG[c*64+lane];
  float tacc = cj*gsl;
  #pragma unroll
  for(int c=0;c<64;c++) tacc += vj[c]*gv[c];
  #pragma unroll
  for(int rr=0;rr<8;rr++){
    int r = wid*8+rr;
    const float* mrow = Mj + r*64;                // wave-uniform -> s_load
    float acc = uj[r]*gsl;
    #pragma unroll
    for(int c=0;c<64;c++) acc += mrow[c]*gv[c];
    sT[r*64+lane]=acc;
  }
  if(wid==0) stv[lane]=tacc;
}

// ------- LN0 apply + Gram (512 thr) + MLP ride-along + prep-reduce blocks ---------
__global__ __launch_bounds__(512) void k_ln0ag(const float* __restrict__ xy,
    const float* __restrict__ g, const float* __restrict__ bb,
    const float* __restrict__ lnp,
    float* __restrict__ Vin, float* __restrict__ Gpart, float* __restrict__ gspart,
    MlpW P, int mlp_off, float* __restrict__ ws)
{
  __shared__ float sV[4096];
  int blk = blockIdx.x;
  int tid = threadIdx.x, lane = tid&63;
  int wid = __builtin_amdgcn_readfirstlane(tid>>6);
  if(blk >= 512){
    int j = blk-512;                              // 4 reduce blocks
    const float* mp0 = ws + OFF_GPB + (size_t)(j*16)*MP_STRIDE;
    for(int e=tid; e<1024; e+=512){
      float4 s={0,0,0,0};
      for(int ch=0; ch<16; ch++){
        float4 v = *(const float4*)&mp0[(size_t)ch*MP_STRIDE + e*4];
        s.x+=v.x; s.y+=v.y; s.z+=v.z; s.w+=v.w;
      }
      s.x*=SCALE; s.y*=SCALE; s.z*=SCALE; s.w*=SCALE;
      *(float4*)&ws[OFF_M + j*4096 + e*4] = s;
    }
    if(tid<64){
      float su=0.f, sv=0.f;
      for(int ch=0; ch<16; ch++){
        su += mp0[(size_t)ch*MP_STRIDE + 4096 + tid];
        sv += mp0[(size_t)ch*MP_STRIDE + 4160 + tid];
      }
      ws[OFF_U + j*64+tid] = su*SCALE;
      ws[OFF_V + j*64+tid] = sv*SCALE;
    }
    if(tid==0){
      float sc=0.f;
      for(int ch=0; ch<16; ch++) sc += mp0[(size_t)ch*MP_STRIDE + 4224];
      ws[OFF_C + j] = sc*SCALE;
    }
    return;
  }
  if(blk >= 256){
    mlp_unit(P, mlp_off + (blk-256)*2 + (wid>>2), wid&3, lane);
    return;
  }
  int b = blk>>5, ch = blk&31;
  float s=0.f, ss=0.f;
  #pragma unroll
  for(int k2=0;k2<16;k2++){ s += lnp[(b*16+k2)*2]; ss += lnp[(b*16+k2)*2+1]; }
  float mean = s*(1.0f/131072.0f);
  float var  = ss*(1.0f/131072.0f) - mean*mean;
  float inv  = 1.0f/sqrtf(var+EPSC);
  const float4* x4 = (const float4*)(xy + ((size_t)b*2048 + ch*64)*64);
  const float4* g4 = (const float4*)(g  + (size_t)ch*4096);
  const float4* b4 = (const float4*)(bb + (size_t)ch*4096);
  float4* vo4 = (float4*)(Vin + ((size_t)b*2048 + ch*64)*64);
  float4* sv4 = (float4*)sV;
  #pragma unroll
  for(int e=0;e<2;e++){
    int idx = tid + e*512;
    float4 xv=x4[idx], gv=g4[idx], bv=b4[idx];
    float4 r;
    r.x=(xv.x-mean)*inv*gv.x+bv.x;
    r.y=(xv.y-mean)*inv*gv.y+bv.y;
    r.z=(xv.z-mean)*inv*gv.z+bv.z;
    r.w=(xv.w-mean)*inv*gv.w+bv.w;
    vo4[idx]=r; sv4[idx]=r;
  }
  __syncthreads();
  gram_tile8(sV, sV, wid, lane, Gpart+((size_t)(b*32+ch))*4096, gspart+(b*32+ch)*64);
}

// -------- layer (512 threads) + ride-along: MLP (emode 0) or transpose (emode 1) ---
__global__ __launch_bounds__(512) void k_layer(
    float* __restrict__ Vin, const float* __restrict__ xy,
    const float* __restrict__ Gsrc, const float* __restrict__ gssrc,
    float* __restrict__ Gdst, float* __restrict__ gsdst,
    const float* __restrict__ Mg, const float* __restrict__ ug,
    const float* __restrict__ vg, const float* __restrict__ cg,
    const float* __restrict__ lng, const float* __restrict__ lnb,
    int j, int cross, MlpW P, int mlp_off,
    unsigned short* __restrict__ wtg, unsigned short* __restrict__ wftg,
    float* __restrict__ wsp2, int emode)
{
  __shared__ __align__(16) float sV[4096];
  __shared__ __align__(16) float sT[4096];
  __shared__ __align__(16) float sG[4096];
  __shared__ float stv[64];
  int blk = blockIdx.x, tid = threadIdx.x;
  int lane = tid&63;
  int wid = __builtin_amdgcn_readfirstlane(tid>>6);
  if(blk >= 256){
    if(emode == 0){
      mlp_unit(P, mlp_off + (blk-256)*2 + (wid>>2), wid&3, lane);
    } else {
      int half = tid>>8;                          // waves 0-3 / 4-7
      int unit = (blk-256)*2 + half;              // 0..511
      int utid = tid & 255;
      int mat = unit>>8, tile = unit&255;
      int nt = tile>>4, jt = tile&15;
      unsigned short* S = (unsigned short*)(half? sT : sV);
      transpose_unit(mat? P.wfo : P.wo, mat? wftg : wtg,
                     wsp2 + (mat*16 + nt)*1024, nt*64, jt*64, S, utid);
    }
    return;
  }
  int b = blk>>5, ch = blk&31;
  float* vbase = Vin + ((size_t)b*2048 + ch*64)*64;
  {
    const float4* vb4=(const float4*)vbase;
    float4* sv4=(float4*)sV;
    #pragma unroll
    for(int e=0;e<2;e++) sv4[tid+e*512]=vb4[tid+e*512];
  }
  {
    float4 a0={0,0,0,0},a1={0,0,0,0};
    const float4* gp4 = (const float4*)(Gsrc + (size_t)b*32*4096) + tid*2;
    for(int c=0;c<32;c++){
      const float4* p = gp4 + c*1024;
      float4 v0=p[0],v1=p[1];
      a0.x+=v0.x;a0.y+=v0.y;a0.z+=v0.z;a0.w+=v0.w;
      a1.x+=v1.x;a1.y+=v1.y;a1.z+=v1.z;a1.w+=v1.w;
    }
    float4* sg4=(float4*)sG + tid*2;
    sg4[0]=a0; sg4[1]=a1;
  }
  float gsl=0.f;
  for(int c=0;c<32;c++) gsl += gssrc[(b*32+c)*64+lane];
  __syncthreads();
  build_T8(sG, Mg+j*4096, ug+j*64, vg+j*64, cg[j], gsl, wid, lane, sT, stv);
  __syncthreads();
  float Tcol[64];
  #pragma unroll
  for(int c=0;c<64;c++) Tcol[c]=sT[c*64+lane];
  float tvl=stv[lane];
  float gl=lng[j*64+lane], bl=lnb[j*64+lane];
  #pragma unroll
  for(int rr=0;rr<8;rr++){
    int r=wid*8+rr;
    const float4* rp=(const float4*)(sV + r*64);
    float vold = sV[r*64+lane];
    float m=tvl;
    #pragma unroll
    for(int c4=0;c4<16;c4++){
      float4 vv=rp[c4];
      m += vv.x*Tcol[c4*4]+vv.y*Tcol[c4*4+1]+vv.z*Tcol[c4*4+2]+vv.w*Tcol[c4*4+3];
    }
    m*=DXDY;
    float mean=wsum64(m)*(1.f/64.f);
    float d=m-mean;
    float var=wsum64(d*d)*(1.f/64.f);
    float y=d*(1.f/sqrtf(var+EPSC))*gl+bl+vold;
    vbase[r*64+lane]=y;
    sV[r*64+lane]=y;
  }
  __syncthreads();
  if(!cross){
    gram_tile8(sV, sV, wid, lane, Gdst+((size_t)(b*32+ch))*4096, gsdst+(b*32+ch)*64);
  } else if(ch<16){
    const float4* x4=(const float4*)(xy + ((size_t)b*2048+ch*64)*64);
    float4* sx4=(float4*)sG;
    #pragma unroll
    for(int e=0;e<2;e++) sx4[tid+e*512]=x4[tid+e*512];
    __syncthreads();
    gram_tile8(sV, sG, wid, lane, Gdst+((size_t)(b*16+ch))*4096, gsdst+(b*16+ch)*64);
  }
}

// ------ P = Wt^T-GEMM via MFMA: D[16jj x 64f] per wave, K=512 per block (ns=2) -----
__global__ __launch_bounds__(256) void k_pw(
    const unsigned short* __restrict__ WtG, const unsigned short* __restrict__ WftG,
    const float* __restrict__ Vin,
    float* __restrict__ P0, float* __restrict__ P1)
{
  __shared__ __align__(16) unsigned short sVu[64*72];   // [f][n-padded] bf16
  __shared__ __align__(16) unsigned short sVf[64*72];
  int bid = blockIdx.x;                 // 256 = b(8) x jjc(16) x ns(2)
  int ns = bid&1, jjc = (bid>>1)&15, b = bid>>5;
  int tid = threadIdx.x, lane = tid&63;
  int wid = __builtin_amdgcn_readfirstlane(tid>>6);
  int jl = lane&15, grp = lane>>4;
  int jjw = jjc*64 + wid*16;
  const float* Vu = Vin + (size_t)b*131072;
  const float* Vf = Vu + 65536;
  f32x4 acc[4] = {{0,0,0,0},{0,0,0,0},{0,0,0,0},{0,0,0,0}};
  int np = tid&31, fq = tid>>5;         // staging: 32 n-pairs x 8 f-groups
  unsigned* Su = (unsigned*)sVu;
  unsigned* Sf = (unsigned*)sVf;
  for(int step=0; step<8; step++){
    int nb = ns*512 + step*64;
    {
      const float* u0 = Vu + (size_t)(nb + 2*np)*64 + fq*8;
      const float* f0 = Vf + (size_t)(nb + 2*np)*64 + fq*8;
      float ua[8], ub[8], fa[8], fb[8];
      *(float4*)&ua[0] = *(const float4*)u0;      *(float4*)&ua[4] = *(const float4*)(u0+4);
      *(float4*)&ub[0] = *(const float4*)(u0+64); *(float4*)&ub[4] = *(const float4*)(u0+68);
      *(float4*)&fa[0] = *(const float4*)f0;      *(float4*)&fa[4] = *(const float4*)(f0+4);
      *(float4*)&fb[0] = *(const float4*)(f0+64); *(float4*)&fb[4] = *(const float4*)(f0+68);
      #pragma unroll
      for(int e=0;e<8;e++){
        Su[((fq*8+e)*72 + 2*np)>>1] = cvt2bf(ua[e], ub[e]);
        Sf[((fq*8+e)*72 + 2*np)>>1] = cvt2bf(fa[e], fb[e]);
      }
    }
    __syncthreads();
    #pragma unroll
    for(int ks=0; ks<2; ks++){
      int kk = ks*32;
      bf16x8 aw  = *(const bf16x8*)&WtG [(size_t)(jjw+jl)*1024 + nb + kk + grp*8];
      bf16x8 awf = *(const bf16x8*)&WftG[(size_t)(jjw+jl)*1024 + nb + kk + grp*8];
      #pragma unroll
      for(int ft=0; ft<4; ft++){
        bf16x8 bu = *(const bf16x8*)&sVu[(ft*16+jl)*72 + kk + grp*8];
        bf16x8 bv = *(const bf16x8*)&sVf[(ft*16+jl)*72 + kk + grp*8];
        acc[ft] = __builtin_amdgcn_mfma_f32_16x16x32_bf16(aw,  bu, acc[ft], 0,0,0);
        acc[ft] = __builtin_amdgcn_mfma_f32_16x16x32_bf16(awf, bv, acc[ft], 0,0,0);
      }
    }
    __syncthreads();
  }
  float* Pd = (ns? P1 : P0) + ((size_t)b*1024 + jjw)*64;
  #pragma unroll
  for(int ft=0; ft<4; ft++){
    #pragma unroll
    for(int r=0;r<4;r++){
      int row = grp*4 + r;
      Pd[(size_t)row*64 + ft*16 + jl] = acc[ft][r];
    }
  }
}

// ---------------- final (512 threads): redundant T3 build + out ----------------
__global__ __launch_bounds__(512) void k_final(
    const float* __restrict__ Gp2, const float* __restrict__ gsp2,
    const float* __restrict__ Mg, const float* __restrict__ ug,
    const float* __restrict__ vg, const float* __restrict__ cg,
    const float* __restrict__ P0, const float* __restrict__ P1,
    const float* __restrict__ wsp2,
    float* __restrict__ out)
{
  __shared__ float sG[4096];
  __shared__ float sT[4096];
  __shared__ float stv[64];
  int blk = blockIdx.x, tid = threadIdx.x;       // grid 256
  int lane = tid&63;
  int wid = __builtin_amdgcn_readfirstlane(tid>>6);
  int b = blk>>5, rg = blk&31;
  {
    float4 a0={0,0,0,0},a1={0,0,0,0};
    const float4* gp4 = (const float4*)(Gp2 + (size_t)b*16*4096) + tid*2;
    for(int c=0;c<16;c++){
      const float4* p = gp4 + c*1024;
      float4 v0=p[0],v1=p[1];
      a0.x+=v0.x;a0.y+=v0.y;a0.z+=v0.z;a0.w+=v0.w;
      a1.x+=v1.x;a1.y+=v1.y;a1.z+=v1.z;a1.w+=v1.w;
    }
    float4* sg4=(float4*)sG + tid*2;
    sg4[0]=a0; sg4[1]=a1;
  }
  float gsl=0.f;
  for(int c=0;c<16;c++) gsl += gsp2[(b*16+c)*64+lane];
  __syncthreads();
  build_T8(sG, Mg+3*4096, ug+3*64, vg+3*64, cg[3], gsl, wid, lane, sT, stv);
  __syncthreads();
  float Tcol[64];
  #pragma unroll
  for(int c=0;c<64;c++) Tcol[c]=sT[c*64+lane];
  float t3l=stv[lane];
  #pragma unroll
  for(int rw=0;rw<4;rw++){
    int jj=rg*32+wid*4+rw;
    float p = P0[((size_t)b*1024+jj)*64+lane]
            + P1[((size_t)b*1024+jj)*64+lane];
    float wsm = 0.f;
    #pragma unroll
    for(int c=0;c<32;c++) wsm += wsp2[c*1024+jj];
    float acc=wsm*t3l;
    #pragma unroll
    for(int c=0;c<64;c++) acc += __shfl(p,c)*Tcol[c];
    out[((size_t)(b*1024)+jj)*64+lane]=acc*(DXDY*DXDY);
  }
}

extern "C" void kernel_launch(void* const* d_in, const int* in_sizes, int n_in,
                              void* d_out, int out_size, void* d_ws, size_t ws_size,
                              hipStream_t stream)
{
  (void)in_sizes; (void)n_in; (void)out_size; (void)ws_size;
  const float* xy   = (const float*)d_in[0];
  const float* kW0  = (const float*)d_in[1];
  const float* kb0  = (const float*)d_in[2];
  const float* kW1  = (const float*)d_in[3];
  const float* kb1  = (const float*)d_in[4];
  const float* kW2  = (const float*)d_in[5];
  const float* kb2  = (const float*)d_in[6];
  const float* fW0  = (const float*)d_in[7];
  const float* fb0  = (const float*)d_in[8];
  const float* fW1  = (const float*)d_in[9];
  const float* fb1  = (const float*)d_in[10];
  const float* fW2  = (const float*)d_in[11];
  const float* fb2  = (const float*)d_in[12];
  const float* Wq   = (const float*)d_in[13];
  const float* bq   = (const float*)d_in[14];
  const float* Wk   = (const float*)d_in[15];
  const float* bk   = (const float*)d_in[16];
  const float* ln0g = (const float*)d_in[17];
  const float* ln0b = (const float*)d_in[18];
  const float* lng  = (const float*)d_in[19];
  const float* lnb  = (const float*)d_in[20];
  float* out = (float*)d_out;
  float* ws  = (float*)d_ws;

  float* lnp    = ws+OFF_LNP;
  float* Mg     = ws+OFF_M;
  float* ug     = ws+OFF_U;
  float* vg     = ws+OFF_V;
  float* cg     = ws+OFF_C;
  float* wsp2   = ws+OFF_WSP2;
  float* Vin    = ws+OFF_VIN;
  float* weight = ws+OFF_W;
  float* weightf= ws+OFF_WF;
  float* GPA    = ws+OFF_GPA;
  float* GSA    = ws+OFF_GSA;
  float* GPB    = ws+OFF_GPB;
  float* GSB    = ws+OFF_GSB;
  unsigned short* Wt  = (unsigned short*)(ws+OFF_P);
  unsigned short* Wft = Wt + 1048576;
  float* P1 = GPB + 524288;            // GPB upper half (lower = cross-gram)

  MlpW P = {kW0,kb0,kW1,kb1,kW2,kb2, fW0,fb0,fW1,fb1,fW2,fb2, weight, weightf};

  // MLP units 0..511 start in k_pre (input-only dependency); 512..1023 in k_ln0ag;
  // 1024..1535 in k_layer(0); 1536..2047 in k_layer(1). All finish before the
  // j=2 transpose consumes weight/weightf.
  k_pre<<<704, 256, 0, stream>>>(xy, Wq, bq, Wk, bk, ws, P);
  k_ln0ag<<<516, 512, 0, stream>>>(xy, ln0g, ln0b, lnp, Vin, GPA, GSA, P, 512, ws);
  k_layer<<<512, 512, 0, stream>>>(Vin, xy, GPA, GSA, GPB, GSB,
                                   Mg, ug, vg, cg, lng, lnb, 0, 0, P, 1024,
                                   Wt, Wft, wsp2, 0);
  k_layer<<<512, 512, 0, stream>>>(Vin, xy, GPB, GSB, GPA, GSA,
                                   Mg, ug, vg, cg, lng, lnb, 1, 0, P, 1536,
                                   Wt, Wft, wsp2, 0);
  // j=2: carrier (256) + 256 transpose blocks (weight final after j=1)
  k_layer<<<512, 512, 0, stream>>>(Vin, xy, GPA, GSA, GPB, GSB,
                                   Mg, ug, vg, cg, lng, lnb, 2, 1, P, 0,
                                   Wt, Wft, wsp2, 1);

  // GPA dead after j=2 -> P ns0; GPB upper -> P ns1
  k_pw<<<256, 256, 0, stream>>>(Wt, Wft, Vin, GPA, P1);
  k_final<<<256, 512, 0, stream>>>(GPB, GSB, Mg, ug, vg, cg, GPA, P1, wsp2, out);
}